// Round 5
// baseline (148.489 us; speedup 1.0000x reference)
//
#include <hip/hip_runtime.h>
#include <math.h>

#define NUM_TOKENS 16384
#define NUM_HEADS  32
#define HEAD_SIZE  128
#define TOTAL_PAIRS (NUM_TOKENS * NUM_HEADS)   // 524288
#define NTHREADS 256

typedef float vfloat4 __attribute__((ext_vector_type(4)));

// Fused merge, head-major group mapping.
// Group id (gid) == lse index (head*NUM_TOKENS + token), so:
//   - p_lse/s_lse loads are coalesced (8 consecutive floats per block)
//   - out_lse stores are coalesced
// Each 32-lane group handles one (token, head) pair: lane loads float4 #lane
// of prefix/suffix (512B dense segment per group), merged with per-group
// scales, stored non-temporally (don't pollute L3 -> keep it for the reads).
__global__ __launch_bounds__(NTHREADS) void merge_attn_states_kernel(
    const float* __restrict__ p_out,   // [NUM_TOKENS, NUM_HEADS, HEAD_SIZE]
    const float* __restrict__ p_lse,   // [NUM_HEADS, NUM_TOKENS]
    const float* __restrict__ s_out,   // [NUM_TOKENS, NUM_HEADS, HEAD_SIZE]
    const float* __restrict__ s_lse,   // [NUM_HEADS, NUM_TOKENS]
    float* __restrict__ out,           // [NUM_TOKENS, NUM_HEADS, HEAD_SIZE]
    float* __restrict__ out_lse)       // [NUM_HEADS, NUM_TOKENS]
{
    const int gid  = blockIdx.x * 8 + (threadIdx.x >> 5);  // == lse_idx
    const int lane = threadIdx.x & 31;
    const int head  = gid >> 14;             // / NUM_TOKENS
    const int token = gid & (NUM_TOKENS - 1);
    const int pair  = token * NUM_HEADS + head;

    // Issue all loads up front (streams first, then the coalesced LSE pair).
    const size_t base = (size_t)pair * HEAD_SIZE;
    const vfloat4* __restrict__ pv = reinterpret_cast<const vfloat4*>(p_out + base);
    const vfloat4* __restrict__ sv = reinterpret_cast<const vfloat4*>(s_out + base);
    vfloat4 a = pv[lane];
    vfloat4 b = sv[lane];
    float pl = p_lse[gid];
    float sl = s_lse[gid];

    // +inf -> -inf sanitization (matches vLLM merge_attn_states)
    pl = (pl == INFINITY) ? -INFINITY : pl;
    sl = (sl == INFINITY) ? -INFINITY : sl;

    const float m  = fmaxf(pl, sl);
    const float pe = __expf(pl - m);
    const float se = __expf(sl - m);
    const float d  = pe + se;
    const float inv = __builtin_amdgcn_rcpf(d);
    const float ps = pe * inv;
    const float ss = se * inv;

    if (lane == 0) {
        out_lse[gid] = __logf(d) + m;
    }

    vfloat4 r;
    r.x = fmaf(a.x, ps, b.x * ss);
    r.y = fmaf(a.y, ps, b.y * ss);
    r.z = fmaf(a.z, ps, b.z * ss);
    r.w = fmaf(a.w, ps, b.w * ss);
    __builtin_nontemporal_store(r, reinterpret_cast<vfloat4*>(out + base) + lane);
}

extern "C" void kernel_launch(void* const* d_in, const int* in_sizes, int n_in,
                              void* d_out, int out_size, void* d_ws, size_t ws_size,
                              hipStream_t stream) {
    const float* p_out = (const float*)d_in[0];  // prefix_output
    const float* p_lse = (const float*)d_in[1];  // prefix_lse
    const float* s_out = (const float*)d_in[2];  // suffix_output
    const float* s_lse = (const float*)d_in[3];  // suffix_lse

    float* out     = (float*)d_out;
    float* out_lse = (float*)d_out + (size_t)NUM_TOKENS * NUM_HEADS * HEAD_SIZE;

    const int blocks = TOTAL_PAIRS / 8;   // 65536 blocks x 256 threads
    merge_attn_states_kernel<<<blocks, NTHREADS, 0, stream>>>(
        p_out, p_lse, s_out, s_lse, out, out_lse);
}